// Round 3
// baseline (799.804 us; speedup 1.0000x reference)
//
#include <hip/hip_runtime.h>
#include <cstdint>
#include <cstddef>

// ---------- types ----------
typedef __bf16  bf16x8f __attribute__((ext_vector_type(8)));      // MFMA A/B operand (4 VGPRs)
typedef unsigned short u16x8 __attribute__((ext_vector_type(8))); // storage view of 8 bf16
typedef float   f32x16 __attribute__((ext_vector_type(16)));      // MFMA 32x32 C/D operand

__device__ __forceinline__ unsigned short f2bf(float f) {
    union { float f; uint32_t u; } c; c.f = f;
    uint32_t u = c.u;
    return (unsigned short)((u + 0x7fffu + ((u >> 16) & 1u)) >> 16);  // RNE
}

// tanh(x) = 1 - 2/(e^{2x}+1); exact at +/-inf, ~1e-6 abs err
__device__ __forceinline__ float fast_tanh(float x) {
    float e = __builtin_exp2f(2.885390081777927f * x);   // e^{2x}
    return 1.0f - 2.0f * __builtin_amdgcn_rcpf(e + 1.0f);
}

// async 16B global -> LDS (DMA; LDS dest is wave-uniform base + lane*16)
__device__ __forceinline__ void load16_lds(const void* g, unsigned short* l) {
    __builtin_amdgcn_global_load_lds(
        (const __attribute__((address_space(1))) unsigned int*)g,
        (__attribute__((address_space(3))) unsigned int*)l,
        16, 0, 0);
}

// ---------- kernel 0: detect mask storage layout ----------
__global__ __launch_bounds__(256)
void detect_mask(const unsigned char* __restrict__ m, int* __restrict__ flag) {
    __shared__ int s_gt1, s_off;
    if (threadIdx.x == 0) { s_gt1 = 0; s_off = 0; }
    __syncthreads();
    int gt1 = 0, off = 0;
    for (int k = threadIdx.x; k < 4096; k += 256) {
        unsigned char b = m[k];
        if (b > 1) gt1 = 1;
        if ((k & 3) && b) off = 1;
    }
    if (gt1) atomicOr(&s_gt1, 1);
    if (off) atomicOr(&s_off, 1);
    __syncthreads();
    if (threadIdx.x == 0) *flag = (!s_gt1 && s_off) ? 1 : 0;
}

// ---------- kernel 1: cast x fp32 -> bf16 ----------
__global__ __launch_bounds__(256)
void cast_f32_bf16(const float* __restrict__ in, unsigned short* __restrict__ out, int n) {
    int tid = blockIdx.x * blockDim.x + threadIdx.x;
    int stride = gridDim.x * blockDim.x;
    for (int e = tid * 4; e < n; e += stride * 4) {
        float4 v = *(const float4*)(in + e);
        ushort4 o;
        o.x = f2bf(v.x); o.y = f2bf(v.y); o.z = f2bf(v.z); o.w = f2bf(v.w);
        *(ushort4*)(out + e) = o;
    }
}

// ---------- kernel 2: masked weight -> bf16 ----------
__global__ __launch_bounds__(256)
void mask_cast(const float* __restrict__ w, const void* __restrict__ mv,
               const int* __restrict__ flag, unsigned short* __restrict__ out, int n) {
    const bool u8 = (*flag != 0);
    int tid = blockIdx.x * blockDim.x + threadIdx.x;
    int stride = gridDim.x * blockDim.x;
    for (int e = tid * 4; e < n; e += stride * 4) {
        float4 v = *(const float4*)(w + e);
        int m0, m1, m2, m3;
        if (u8) {
            uchar4 mm = *(const uchar4*)((const unsigned char*)mv + e);
            m0 = mm.x; m1 = mm.y; m2 = mm.z; m3 = mm.w;
        } else {
            int4 mm = ((const int4*)mv)[e >> 2];
            m0 = mm.x; m1 = mm.y; m2 = mm.z; m3 = mm.w;
        }
        ushort4 o;
        o.x = m0 ? f2bf(v.x) : (unsigned short)0;
        o.y = m1 ? f2bf(v.y) : (unsigned short)0;
        o.z = m2 ? f2bf(v.z) : (unsigned short)0;
        o.w = m3 ? f2bf(v.w) : (unsigned short)0;
        *(ushort4*)(out + e) = o;
    }
}

// ---------- GEMM: C = tanh(A[M,K] x W[N,K]^T + bias) ----------
// 256x256 tile, BK=64, 512 thr = 8 waves (2Mx4N), per-wave 128x64 out via
// mfma_f32_32x32x16_bf16 (acc[4][2] f32x16).
// Phase = (buf, kp): 12 ds_read_b128 (8 A + 4 B, A shared across both nt ->
// 24 reads/wave/K-tile, the per-wave minimum), 2 stage units (4 DMA), 16 MFMA,
// then ONE s_barrier. No mid-phase barrier: waves drift within a phase, so
// one wave's MFMA overlaps another wave's LDS-port drain (port || MFMA pipes;
// with 1 block/CU there is no other block to provide that overlap).
// Sync correctness:
//   WAR: every stage targets units whose last reader is >=1 phase earlier;
//        the end-of-phase barrier separates them (no wave can be a phase
//        behind once any wave passed that barrier).
//   RAW: counted s_waitcnt vmcnt(2) before the end barrier of P2 and P4 only
//        (at those points exactly the 2 not-yet-needed a01 loads are allowed
//        outstanding). Never vmcnt(0) in the main loop.
// Staging per iteration (2 K-tiles: e=2t buf0, o=2t+1 buf1):
//   P1: a23(o),b0(o)->buf1      P2: b1(o)->buf1, a01(e+2)->buf0   [vm2]
//   P3: a23(e+2),b0(e+2)->buf0  P4: b1(e+2)->buf0, a01(o+2)->buf1 [vm2]
// LDS bank swizzle (pre-applied to GLOBAL source so the linear-dest
// global_load_lds stays legal, rule #21):
//   A rows = 64 B (4 chunks): chunk ^= (row>>1)&3; B rows = 128 B (8 chunks):
//   chunk ^= n&7. Measured r2: 4 cyc conflict per read residue.
// XCD map: by in low 3 bits (same-A-panel blocks on one XCD; 197 MB fetch r2).
// Epilogue mapping (HW-verified): col=lane&31, row=(reg&3)+8*(reg>>2)+4*(lane>>5).
template <typename OutT, bool FUSE>
__global__ __launch_bounds__(512, 2)
void gemm256(const unsigned short* __restrict__ A,
             const unsigned short* __restrict__ W,
             const float* __restrict__ bias,
             OutT* __restrict__ out,
             const float* __restrict__ w1, const float* __restrict__ b1,
             const float* __restrict__ w2, const float* __restrict__ b2,
             int N, int K, int lbx) {
    // [buf(2)][ A: 2 units x 8192 | B: 2 units x 8192 ] shorts = 128 KiB
    __shared__ __align__(16) unsigned short lds[65536];

    const int t    = threadIdx.x;
    const int lane = t & 63;
    const int wave = t >> 6;
    const int l31  = lane & 31;
    const int lh   = lane >> 5;
    const int wrow = (wave >> 2) * 128;
    const int wcol = (wave & 3) * 64;

    const int id = blockIdx.x;
    const int bx = (id >> 3) & ((1 << lbx) - 1);
    const int by = (id & 7) | ((id >> (3 + lbx)) << 3);
    const int bm = by * 256, bn = bx * 256;

    const char* Au = (const char*)(A + (size_t)bm * K);
    const char* Wu = (const char*)(W + (size_t)bn * K);

    // ---- staging source byte offsets (loop-invariant, per-thread) ----
    uint32_t aSrc[2], bSrc[2][2];
#pragma unroll
    for (int j = 0; j < 2; ++j) {
        const int u = t + j * 512;
        { const int r = u >> 2, c = u & 3;
          aSrc[j] = (uint32_t)((r * K + ((c ^ ((r >> 1) & 3)) << 3)) * 2); }
        { const int rl = u >> 3, c = u & 7;
#pragma unroll
          for (int Un = 0; Un < 2; ++Un) {
              const int n = (rl & 31) + ((rl >> 5) << 6) + Un * 32;
              bSrc[Un][j] = (uint32_t)((n * K + ((c ^ (n & 7)) << 3)) * 2);
          } }
    }

    // ---- fragment read address pieces (shorts) ----
    int aRow[4];
#pragma unroll
    for (int mt = 0; mt < 4; ++mt) aRow[mt] = (wrow + mt * 32 + l31) * 32;
    int aSwz[2];
#pragma unroll
    for (int j = 0; j < 2; ++j) aSwz[j] = ((j * 2 + lh) ^ ((l31 >> 1) & 3)) << 3;
    int bBase[2];
#pragma unroll
    for (int nt = 0; nt < 2; ++nt)
        bBase[nt] = 16384 + ((((wcol >> 5) + nt) & 1) * 8192)
                  + (((wcol + nt * 32) >> 6) * 2048) + l31 * 64;
    int bSwz[4];
#pragma unroll
    for (int kp = 0; kp < 2; ++kp)
#pragma unroll
        for (int j = 0; j < 2; ++j)
            bSwz[kp * 2 + j] = ((kp * 4 + j * 2 + lh) ^ (l31 & 7)) << 3;

#define STAGE_A(buf, Uk, kB) do {                                              \
    const char* g_ = Au + (kB);                                                \
    unsigned short* l_ = lds + (buf) * 32768 + (Uk) * 8192 + t * 8;            \
    load16_lds(g_ + aSrc[0] + (Uk) * 64, l_);                                  \
    load16_lds(g_ + aSrc[1] + (Uk) * 64, l_ + 4096);                           \
} while (0)

#define STAGE_B(buf, Un, kB) do {                                              \
    const char* g_ = Wu + (kB);                                                \
    unsigned short* l_ = lds + (buf) * 32768 + 16384 + (Un) * 8192 + t * 8;    \
    load16_lds(g_ + bSrc[Un][0], l_);                                          \
    load16_lds(g_ + bSrc[Un][1], l_ + 4096);                                   \
} while (0)

#define BAR    asm volatile("s_barrier" ::: "memory")
#define VMW2   asm volatile("s_waitcnt vmcnt(2)" ::: "memory")

// one phase: 12 ds_read_b128 + 2 stage units issued, MFMA (prio 1), ONE barrier
#define PHASE(buf, kp, STAGE_STMT) do {                                        \
    u16x8 aF[4][2], bF[2][2];                                                  \
    const unsigned short* Lb_ = lds + (buf) * 32768;                           \
    _Pragma("unroll")                                                          \
    for (int j_ = 0; j_ < 2; ++j_) {                                           \
        _Pragma("unroll")                                                      \
        for (int mt_ = 0; mt_ < 4; ++mt_)                                      \
            aF[mt_][j_] = *(const u16x8*)(Lb_ + (kp) * 8192 + aRow[mt_] + aSwz[j_]); \
        _Pragma("unroll")                                                      \
        for (int nt_ = 0; nt_ < 2; ++nt_)                                      \
            bF[nt_][j_] = *(const u16x8*)(Lb_ + bBase[nt_] + bSwz[(kp) * 2 + j_]); \
    }                                                                          \
    STAGE_STMT;                                                                \
    __builtin_amdgcn_s_setprio(1);                                             \
    _Pragma("unroll")                                                          \
    for (int j_ = 0; j_ < 2; ++j_)                                             \
        _Pragma("unroll")                                                      \
        for (int mt_ = 0; mt_ < 4; ++mt_)                                      \
            _Pragma("unroll")                                                  \
            for (int nt_ = 0; nt_ < 2; ++nt_)                                  \
                acc[mt_][nt_] = __builtin_amdgcn_mfma_f32_32x32x16_bf16(       \
                    __builtin_bit_cast(bf16x8f, aF[mt_][j_]),                  \
                    __builtin_bit_cast(bf16x8f, bF[nt_][j_]),                  \
                    acc[mt_][nt_], 0, 0, 0);                                   \
    __builtin_amdgcn_s_setprio(0);                                             \
} while (0)

    f32x16 acc[4][2] = {};

    // prologue: buf0 tile0 (4 units) + buf1 a01(tile1); retire tile0, leave a01
    STAGE_A(0, 0, 0); STAGE_A(0, 1, 0); STAGE_B(0, 0, 0); STAGE_B(0, 1, 0);
    STAGE_A(1, 0, 128);
    VMW2;
    BAR;

    const int KB = K * 2;        // bytes; one K-tile = 128 B
    const int KL = KB - 128;     // last-tile byte offset (stage clamp)
    for (int k0 = 0; k0 < KB; k0 += 256) {
        const int kO = k0 + 128;                       // tile o (always valid)
        int kE2 = k0 + 256; if (kE2 > KL) kE2 = KL;    // tile e+2 (clamped)
        int kO2 = k0 + 384; if (kO2 > KL) kO2 = KL;    // tile o+2 (clamped)
        PHASE(0, 0, STAGE_A(1, 1, kO);  STAGE_B(1, 0, kO));        BAR;  // P1
        PHASE(0, 1, STAGE_B(1, 1, kO);  STAGE_A(0, 0, kE2)); VMW2; BAR;  // P2
        PHASE(1, 0, STAGE_A(0, 1, kE2); STAGE_B(0, 0, kE2));       BAR;  // P3
        PHASE(1, 1, STAGE_B(0, 1, kE2); STAGE_A(1, 0, kO2)); VMW2; BAR;  // P4
    }
    // drain DMA before LDS dealloc (next block on this CU reuses our LDS)
    asm volatile("s_waitcnt vmcnt(0)" ::: "memory");

    // ---- epilogue ----
    float w10 = 0, w11 = 0, bb1 = 0, w20 = 0, w21 = 0, bb2 = 0;
    if constexpr (FUSE) {
        w10 = w1[0]; w11 = w1[1]; bb1 = b1[0];
        w20 = w2[0]; w21 = w2[1]; bb2 = b2[0];
    }
#pragma unroll
    for (int nt = 0; nt < 2; ++nt) {
        const int gn = bn + wcol + nt * 32 + l31;
        const float bv = bias[gn];
#pragma unroll
        for (int mt = 0; mt < 4; ++mt) {
#pragma unroll
            for (int reg = 0; reg < 16; ++reg) {
                const int gm = bm + wrow + mt * 32 + (reg & 3) + 8 * (reg >> 2) + 4 * lh;
                float c = fast_tanh(acc[mt][nt][reg] + bv);
                if constexpr (FUSE) {
                    float c1 = __shfl_xor(c, 1);
                    float c2 = __shfl_xor(c, 2);
                    float c3 = __shfl_xor(c, 3);
                    float y10 = fast_tanh(w10 * c  + w11 * c1 + bb1);
                    float y11 = fast_tanh(w10 * c2 + w11 * c3 + bb1);
                    float y   = fast_tanh(w20 * y10 + w21 * y11 + bb2);
                    if ((lane & 3) == 0)
                        out[(size_t)gm * (N >> 2) + (gn >> 2)] = (OutT)y;
                } else {
                    out[(size_t)gm * N + gn] = (OutT)f2bf(c);
                }
            }
        }
    }
#undef STAGE_A
#undef STAGE_B
#undef BAR
#undef VMW2
#undef PHASE
}

// ---------- launch ----------
extern "C" void kernel_launch(void* const* d_in, const int* in_sizes, int n_in,
                              void* d_out, int out_size, void* d_ws, size_t ws_size,
                              hipStream_t stream) {
    constexpr int B   = 16384;
    constexpr int IN  = 4096;
    constexpr int HID = 2048;
    constexpr int CNV = 1024;

    const float* x       = (const float*)d_in[0];
    const void*  mask_ih = d_in[1];
    const void*  mask_hc = d_in[2];
    const float* w_ih    = (const float*)d_in[3];
    const float* b_ih    = (const float*)d_in[4];
    const float* w_hc    = (const float*)d_in[5];
    const float* b_hc    = (const float*)d_in[6];
    const float* w_c1    = (const float*)d_in[7];
    const float* b_c1    = (const float*)d_in[8];
    const float* w_c2    = (const float*)d_in[9];
    const float* b_c2    = (const float*)d_in[10];
    float* out = (float*)d_out;

    // workspace layout (bytes)
    char* ws = (char*)d_ws;
    unsigned short* Xb  = (unsigned short*)(ws);                    // B*IN  bf16
    unsigned short* Wih = (unsigned short*)(ws + 134217728);        // HID*IN bf16
    unsigned short* Whc = (unsigned short*)(ws + 150994944);        // CNV*HID bf16
    unsigned short* Hb  = (unsigned short*)(ws + 155189248);        // B*HID bf16
    int*            flag = (int*)(ws + 222298112);

    detect_mask<<<1, 256, 0, stream>>>((const unsigned char*)mask_ih, flag);

    cast_f32_bf16<<<4096, 256, 0, stream>>>(x, Xb, B * IN);
    mask_cast<<<1024, 256, 0, stream>>>(w_ih, mask_ih, flag, Wih, HID * IN);
    mask_cast<<<256, 256, 0, stream>>>(w_hc, mask_hc, flag, Whc, CNV * HID);

    // GEMM1: [16384,4096] x [2048,4096]^T -> bf16 h ; 64 by x 8 bx = 512 blocks.
    // by in low 3 bits: same-A-panel blocks land on one XCD (197 MB fetch, r2).
    gemm256<unsigned short, false><<<512, 512, 0, stream>>>(
        Xb, Wih, b_ih, Hb, nullptr, nullptr, nullptr, nullptr, HID, IN, 3);

    // GEMM2 + fused double conv: [16384,2048] x [1024,2048]^T -> fp32 [16384,256]
    // 64 by x 4 bx = 256 blocks (1 per CU).
    gemm256<float, true><<<256, 512, 0, stream>>>(
        Hb, Whc, b_hc, out, w_c1, b_c1, w_c2, b_c2, CNV, HID, 2);
}